// Round 9
// baseline (49.384 us; speedup 1.0000x reference)
//
#include <hip/hip_runtime.h>
#include <math.h>

#define Bsz 8
#define HWp (512*512)
#define TS 32
#define SG 36          // s-grid (out + halo 2)
#define MG 34          // m-grid (out + halo 1)
#define XW 40          // x window (out + halo 4)
#define BW 38          // blur window (out + halo 3)
#define NT 448
#define K2E 1442.6950408889634f   // 1000*log2(e)
#define T2q 0.17157287525380993f  // tan^2(22.5 deg)

typedef float f2 __attribute__((ext_vector_type(2)));

#if __has_builtin(__builtin_amdgcn_exp2f)
#define EXP2F(x) __builtin_amdgcn_exp2f(x)
#else
#define EXP2F(x) __expf(0.6931471805599453f*(x))
#endif

__device__ __forceinline__ int refl(int i, int n) {
    i = (i < 0) ? -i : i;
    return (i >= n) ? (2*n - 2 - i) : i;
}
__device__ __forceinline__ float ldsUf(float v) {
    return __uint_as_float(__builtin_amdgcn_readfirstlane(__float_as_uint(v)));
}
__device__ __forceinline__ f2 ldsU2(const float* p) {
    f2 v = *(const f2*)p;
    f2 r; r.x = ldsUf(v.x); r.y = ldsUf(v.y);
    return r;
}

// matsL layout (floats):
//  [0..23]  Apk pairs (A[2j][k],A[2j+1][k]) at [(j*3+k)*2], A=(Psx@(Pg@We))/sum
//  [24..47] Bpk pairs, B=(Psy@(Pg@We))/sum
//  [48..55] midK = K2E*(hi+lo)/2   [56..63] PH = 2^{K2E*(hi-lo)/2}
//  [64..71] PL = 2^{-K2E*(hi-lo)/2} [72..79] wmh = 0.5*wm
//  [80..103] M1 staging (Pg@We), consumed same-wave in prologue
__global__ __launch_bounds__(NT) void k_fused(
    const float* __restrict__ x,
    const float* __restrict__ we, const float* __restrict__ pg,
    const float* __restrict__ psx, const float* __restrict__ psy,
    const float* __restrict__ wm, const float* __restrict__ lowt,
    const float* __restrict__ hight,
    float* __restrict__ out, float e1f, float e12f, float invsum)
{
    __shared__ float sm1[3*XW*XW];   // A/B: x window ; C+: sS(1296) | mS(1156)
    __shared__ float blb[3*BW*BW];   // unnormalized blur (1/sum folded into A,B)
    __shared__ __align__(16) float matsL[104];
    __shared__ int anyS;

    const int b  = blockIdx.z;
    const int x0 = blockIdx.x*TS, y0 = blockIdx.y*TS;
    const int t  = threadIdx.x;
    const bool inter = (blockIdx.x > 0) && ((int)blockIdx.x < (int)gridDim.x-1) &&
                       (blockIdx.y > 0) && ((int)blockIdx.y < (int)gridDim.y-1);

    if (t == 0) anyS = 0;

    // ---- prologue (wave 0 lanes 0..31): fold mats + thresholds into matsL ----
    if (t < 24) {
        int o = t/3, c = t - o*3;
        float a = 0.f;
        #pragma unroll
        for (int k = 0; k < 8; ++k) a = fmaf(pg[o*8+k], we[k*3+c], a);
        matsL[80 + t] = a;                       // M1 staging
        float av = 0.f, bv = 0.f;
        #pragma unroll
        for (int k = 0; k < 8; ++k) {
            float m1 = matsL[80 + k*3 + c];      // same-wave LDS RAW: lockstep-ordered
            av = fmaf(psx[o*8+k], m1, av);
            bv = fmaf(psy[o*8+k], m1, bv);
        }
        av *= invsum; bv *= invsum;              // fold gaussian normalization here
        int pi = ((o>>1)*3 + c)*2 + (o&1);
        matsL[pi]      = av;
        matsL[24 + pi] = bv;
    } else if (t < 32) {
        int o = t - 24;
        float hi = hight[o], lo = lowt[o];
        float d = K2E * 0.5f * (hi - lo);
        matsL[48+o] = K2E * 0.5f * (hi + lo);    // midK
        matsL[56+o] = exp2f(d);                  // PH
        matsL[64+o] = exp2f(-d);                 // PL
        matsL[72+o] = 0.5f * wm[o];              // wmh
    }

    const float* xb = x + (size_t)b*3*HWp;

    // ---- phase A: x window (reflect) -> sm1 ----
    if (inter) {
        const float* xo = xb + (size_t)(y0-4)*512 + (x0-4);
        for (int i = t; i < 3*XW*10; i += NT) {
            int c = i/400; int j = i - c*400; int r = j/10; int q = j - r*10;
            float4 v = *(const float4*)(xo + (size_t)c*HWp + r*512 + q*4);
            *(float4*)&sm1[c*(XW*XW) + r*XW + q*4] = v;
        }
    } else {
        for (int i = t; i < XW*XW; i += NT) {
            int r = i/XW, cc = i - r*XW;
            size_t off = (size_t)refl(y0-4+r,512)*512 + refl(x0-4+cc,512);
            #pragma unroll
            for (int c = 0; c < 3; ++c)
                sm1[c*(XW*XW)+i] = xb[(size_t)c*HWp + off];
        }
    }
    __syncthreads();

    // ---- phase B: separable gaussian (unnormalized) -> blb ----
    if (inter) {
        if (t < 380) {
            int g = t/38, cb = t - g*38, r0 = 4*g;
            #pragma unroll
            for (int c = 0; c < 3; ++c) {
                const float* col = &sm1[c*(XW*XW) + cb];
                float* bo = &blb[c*(BW*BW) + cb];
                float x0v = col[r0*XW], x1v = col[r0*XW+1], x2v = col[r0*XW+2];
                float rp0 = fmaf(e1f, x0v + x2v, x1v);
                x0v = col[(r0+1)*XW]; x1v = col[(r0+1)*XW+1]; x2v = col[(r0+1)*XW+2];
                float rp1 = fmaf(e1f, x0v + x2v, x1v);
                #pragma unroll
                for (int ir = 0; ir < 4; ++ir) {
                    int r = r0 + ir;
                    if (r < BW) {
                        x0v = col[(r+2)*XW]; x1v = col[(r+2)*XW+1]; x2v = col[(r+2)*XW+2];
                        float rp2 = fmaf(e1f, x0v + x2v, x1v);
                        bo[r*BW] = fmaf(e1f, rp0 + rp2, rp1);
                        rp0 = rp1; rp1 = rp2;
                    }
                }
            }
        }
    } else {
        for (int i = t; i < BW*BW; i += NT) {
            int r = i/BW, cc = i - r*BW;
            int iy = refl(y0-3+r,512) - (y0-4);
            int ix = refl(x0-3+cc,512) - (x0-4);
            const int base = iy*XW + ix;
            #pragma unroll
            for (int c = 0; c < 3; ++c) {
                const float* xp = &sm1[c*(XW*XW) + base];
                float crn = xp[-XW-1]+xp[-XW+1]+xp[XW-1]+xp[XW+1];
                float edg = xp[-XW]+xp[-1]+xp[1]+xp[XW];
                blb[c*(BW*BW)+i] = fmaf(e12f, crn, fmaf(e1f, edg, xp[0]));
            }
        }
    }
    __syncthreads();

    // ---- phase C: sobel via rolling regs -> mag/octant (regs, pinned) + s -> sS ----
    f2 mg2[3][4];
    unsigned qk[3];
    const int gC = t/36, csC = t - gC*36, r0C = 3*gC;
    const bool actC = (t < 432);
    if (actC) {
        f2 A2[12], B2[12];
        #pragma unroll
        for (int j = 0; j < 12; ++j) {
            A2[j] = ldsU2(matsL + 2*j);
            B2[j] = ldsU2(matsL + 24 + 2*j);
        }
        float D0[3], D1[3], E0[3], E1[3];
        #pragma unroll
        for (int c = 0; c < 3; ++c) {
            const float* blc = &blb[c*(BW*BW) + csC];
            float p0 = blc[r0C*BW],     p1 = blc[r0C*BW+1],     p2 = blc[r0C*BW+2];
            float q0 = blc[(r0C+1)*BW], q1 = blc[(r0C+1)*BW+1], q2 = blc[(r0C+1)*BW+2];
            D0[c] = p2-p0; E0[c] = fmaf(0.5f, p0+p2, p1);
            D1[c] = q2-q0; E1[c] = fmaf(0.5f, q0+q2, q1);
        }
        #pragma unroll
        for (int ir = 0; ir < 3; ++ir) {
            float txv[3], tyv[3];
            #pragma unroll
            for (int c = 0; c < 3; ++c) {
                const float* wr = &blb[c*(BW*BW) + (r0C+2+ir)*BW + csC];
                float w0 = wr[0], w1 = wr[1], w2 = wr[2];
                float D2 = w2-w0, E2 = fmaf(0.5f, w0+w2, w1);
                txv[c] = fmaf(0.5f, D0[c]+D2, D1[c]);
                tyv[c] = E2 - E0[c];
                D0[c] = D1[c]; D1[c] = D2; E0[c] = E1[c]; E1[c] = E2;
            }
            float s = 0.f;
            unsigned pk = 0;
            #pragma unroll
            for (int j = 0; j < 4; ++j) {
                float gxa = fmaf(A2[j*3].x, txv[0], fmaf(A2[j*3+1].x, txv[1], A2[j*3+2].x*txv[2]));
                float gxb = fmaf(A2[j*3].y, txv[0], fmaf(A2[j*3+1].y, txv[1], A2[j*3+2].y*txv[2]));
                float gya = fmaf(B2[j*3].x, tyv[0], fmaf(B2[j*3+1].x, tyv[1], B2[j*3+2].x*tyv[2]));
                float gyb = fmaf(B2[j*3].y, tyv[0], fmaf(B2[j*3+1].y, tyv[1], B2[j*3+2].y*tyv[2]));
                float gx2a = gxa*gxa, gy2a = gya*gya;
                float gx2b = gxb*gxb, gy2b = gyb*gyb;
                f2 m;
                m.x = __builtin_amdgcn_sqrtf(gx2a + gy2a + 1e-10f);
                m.y = __builtin_amdgcn_sqrtf(gx2b + gy2b + 1e-10f);
                mg2[ir][j] = m;
                s += m.x + m.y;
                unsigned d0 = 1u | (((__float_as_uint(gxa) ^ __float_as_uint(gya)) >> 30) & 2u);
                unsigned q0 = (gx2a <= T2q*gy2a) ? 2u : d0;
                q0 = (gy2a <= T2q*gx2a) ? 0u : q0;
                unsigned d1 = 1u | (((__float_as_uint(gxb) ^ __float_as_uint(gyb)) >> 30) & 2u);
                unsigned q1 = (gx2b <= T2q*gy2b) ? 2u : d1;
                q1 = (gy2b <= T2q*gx2b) ? 0u : q1;
                pk |= (q0 << (4*j)) | (q1 << (4*j+2));
            }
            qk[ir] = pk;
            #pragma unroll
            for (int j = 0; j < 4; ++j) { asm volatile("" : "+v"(mg2[ir][j])); }
            asm volatile("" : "+v"(qk[ir]));
            int rr = r0C + ir;
            int gy_ = y0-2+rr, gx_ = x0-2+csC;
            bool inimg = ((unsigned)gy_ < 512u) && ((unsigned)gx_ < 512u);
            sm1[rr*SG + csC] = inimg ? s : 0.f;   // sS (x window dead)
        }
    }
    __syncthreads();

    // ---- phase D: NMS + single-exp2 double-sigmoid + merge -> mS ----
    bool anyL = false;
    {
        const float* sS = sm1;
        float* mS = sm1 + SG*SG;
        if (actC && csC >= 1 && csC <= 34) {
            f2 mid2[4], ph2[4], pl2[4], wm2[4];
            #pragma unroll
            for (int j = 0; j < 4; ++j) {
                mid2[j] = ldsU2(matsL + 48 + 2*j);
                ph2[j]  = ldsU2(matsL + 56 + 2*j);
                pl2[j]  = ldsU2(matsL + 64 + 2*j);
                wm2[j]  = ldsU2(matsL + 72 + 2*j);
            }
            int ra = r0C-1 < 0 ? 0 : r0C-1;
            const float* pa = &sS[ra*SG + csC];
            const float* pb = &sS[r0C*SG + csC];
            const float* pc = &sS[(r0C+1)*SG + csC];
            float l0=pa[-1], c0=pa[0], r0v=pa[1];
            float l1=pb[-1], c1=pb[0], r1v=pb[1];
            float l2=pc[-1], c2=pc[0], r2v=pc[1];
            #pragma unroll
            for (int ir = 0; ir < 3; ++ir) {
                int r = r0C + ir;
                if (r >= 1 && r <= 34) {
                    float sc = c1;
                    unsigned mask = 0;
                    mask |= ((sc > r1v) && (sc > l1)) ? 1u : 0u;  // E/W
                    mask |= ((sc > r2v) && (sc > l0)) ? 2u : 0u;  // SE/NW
                    mask |= ((sc > c2)  && (sc > c0)) ? 4u : 0u;  // S/N
                    mask |= ((sc > l2)  && (sc > r0v)) ? 8u : 0u; // SW/NE
                    unsigned pk = qk[ir];
                    float m = 0.f;
                    #pragma unroll
                    for (int j = 0; j < 4; ++j) {
                        unsigned ii = pk >> (4*j);
                        float n0 = ((mask >> (ii & 3u)) & 1u)      ? mg2[ir][j].x : 0.f;
                        float n1 = ((mask >> ((ii>>2) & 3u)) & 1u) ? mg2[ir][j].y : 0.f;
                        float e0 = EXP2F(fmaf(n0, -K2E, mid2[j].x));
                        float e1 = EXP2F(fmaf(n1, -K2E, mid2[j].y));
                        float sh0 = __builtin_amdgcn_rcpf(fmaf(e0, ph2[j].x, 1.f));
                        float sl0 = __builtin_amdgcn_rcpf(fmaf(e0, pl2[j].x, 1.f));
                        float sh1 = __builtin_amdgcn_rcpf(fmaf(e1, ph2[j].y, 1.f));
                        float sl1 = __builtin_amdgcn_rcpf(fmaf(e1, pl2[j].y, 1.f));
                        m = fmaf(wm2[j].x, sh0 + sl0, m);
                        m = fmaf(wm2[j].y, sh1 + sl1, m);
                    }
                    mS[(r-1)*MG + (csC-1)] = m;
                    anyL |= (m == 1.0f);
                }
                if (ir < 2) {
                    int rn = r0C + 2 + ir; rn = rn > 35 ? 35 : rn;
                    const float* pn = &sS[rn*SG + csC];
                    l0=l1; c0=c1; r0v=r1v;
                    l1=l2; c1=c2; r1v=r2v;
                    l2=pn[-1]; c2=pn[0]; r2v=pn[1];
                }
            }
        }
    }
    if (anyL) anyS = 1;
    __syncthreads();

    // ---- phase E: one-step hysteresis (reflect) -> out; vector-zero fast path ----
    {
        const float* mS = sm1 + SG*SG;
        float* op = out + (size_t)b*HWp;
        if (anyS == 0) {
            if (t < 256) {
                int row = t >> 3, q = t & 7;
                float4 z = {0.f, 0.f, 0.f, 0.f};
                *(float4*)(op + (size_t)(y0+row)*512 + x0 + q*4) = z;
            }
        } else {
            for (int i2 = t; i2 < TS*TS; i2 += NT) {
                int ty_ = i2>>5, tx_ = i2&31;
                int y = y0 + ty_, xg = x0 + tx_;
                const float* mp = &mS[(ty_+1)*MG + (tx_+1)];
                float mc = mp[0];
                float hy = 0.f;
                if (inter) {
                    #pragma unroll
                    for (int dy = -1; dy <= 1; ++dy)
                        #pragma unroll
                        for (int dx = -1; dx <= 1; ++dx)
                            hy += (mp[dy*MG+dx] == 1.0f) ? 1.25f : 0.f;
                } else {
                    #pragma unroll
                    for (int dy = -1; dy <= 1; ++dy)
                        #pragma unroll
                        for (int dx = -1; dx <= 1; ++dx) {
                            int ly = refl(y+dy,512) - (y0-1);
                            int lx = refl(xg+dx,512) - (x0-1);
                            hy += (mS[ly*MG+lx] == 1.0f) ? 1.25f : 0.f;
                        }
                }
                float strong = (mc == 1.0f) ? mc : 0.f;
                op[(size_t)y*512 + xg] =
                    (((hy > 1.0f) && (mc == 0.5f)) ? mc : 0.f) + strong;
            }
        }
    }
}

extern "C" void kernel_launch(void* const* d_in, const int* in_sizes, int n_in,
                              void* d_out, int out_size, void* d_ws, size_t ws_size,
                              hipStream_t stream) {
    const float* x    = (const float*)d_in[0];
    const float* we   = (const float*)d_in[1];
    const float* pg   = (const float*)d_in[2];
    const float* psx  = (const float*)d_in[3];
    const float* psy  = (const float*)d_in[4];
    const float* wm   = (const float*)d_in[5];
    const float* lowt = (const float*)d_in[6];
    const float* hit  = (const float*)d_in[7];
    float* outp = (float*)d_out;

    // gaussian 3x3 (sigma=3): separable outer([e1,1,e1]) since e2 = e1^2
    double e1 = exp(-1.0/18.0), e2 = exp(-2.0/18.0);
    double sum = 1.0 + 4.0*e1 + 4.0*e2;
    float e1f = (float)e1, e12f = (float)e2, invsum = (float)(1.0/sum);

    k_fused<<<dim3(512/TS, 512/TS, Bsz), dim3(NT), 0, stream>>>(
        x, we, pg, psx, psy, wm, lowt, hit, outp, e1f, e12f, invsum);
}

// Round 10
// 46.453 us; speedup vs baseline: 1.0631x; 1.0631x over previous
//
#include <hip/hip_runtime.h>
#include <math.h>

#define Bsz 8
#define HWp (512*512)
#define TS 32
#define SG 36          // s rows/cols
#define SP 37          // s row stride (padded, odd)
#define MG 34          // m rows/cols
#define MP 35          // m row stride (padded, odd)
#define XW 40          // x window rows/cols (stride 40, float4-aligned)
#define BW 38          // blur rows/cols
#define BP 39          // blur row stride (padded, odd)
#define NT 512
#define K2E 1442.6950408889634f   // 1000*log2(e)
#define T2q 0.17157287525380993f  // tan^2(22.5 deg)

typedef float f2 __attribute__((ext_vector_type(2)));

#if __has_builtin(__builtin_amdgcn_exp2f)
#define EXP2F(x) __builtin_amdgcn_exp2f(x)
#else
#define EXP2F(x) __expf(0.6931471805599453f*(x))
#endif

__device__ __forceinline__ int refl(int i, int n) {
    i = (i < 0) ? -i : i;
    return (i >= n) ? (2*n - 2 - i) : i;
}
__device__ __forceinline__ float ldsUf(float v) {
    return __uint_as_float(__builtin_amdgcn_readfirstlane(__float_as_uint(v)));
}
__device__ __forceinline__ f2 ldsU2(const float* p) {
    f2 v = *(const f2*)p;
    f2 r; r.x = ldsUf(v.x); r.y = ldsUf(v.y);
    return r;
}

// matsL layout (floats):
//  [0..23]  Apk pairs (A[2j][k],A[2j+1][k]) at [(j*3+k)*2], A=(Psx@(Pg@We))/sum
//  [24..47] Bpk pairs, B=(Psy@(Pg@We))/sum
//  [48..55] midK  [56..63] PH  [64..71] PL  [72..79] 0.5*wm
//  [80..103] M1 staging
__global__ __launch_bounds__(NT) void k_fused(
    const float* __restrict__ x,
    const float* __restrict__ we, const float* __restrict__ pg,
    const float* __restrict__ psx, const float* __restrict__ psy,
    const float* __restrict__ wm, const float* __restrict__ lowt,
    const float* __restrict__ hight,
    float* __restrict__ out, float e1f, float e12f, float invsum)
{
    __shared__ float sm1[3*XW*XW];   // A/B: x window ; C+: sS(36x37) | mS(34x35)
    __shared__ float blb[3*BW*BP];   // unnormalized blur, padded stride
    __shared__ __align__(16) float matsL[104];
    __shared__ int anyS;

    const int b  = blockIdx.z;
    const int x0 = blockIdx.x*TS, y0 = blockIdx.y*TS;
    const int t  = threadIdx.x;
    const bool inter = (blockIdx.x > 0) && ((int)blockIdx.x < (int)gridDim.x-1) &&
                       (blockIdx.y > 0) && ((int)blockIdx.y < (int)gridDim.y-1);

    if (t == 0) anyS = 0;

    // ---- prologue (wave 0 lanes 0..31): fold mats + thresholds into matsL ----
    if (t < 24) {
        int o = t/3, c = t - o*3;
        float a = 0.f;
        #pragma unroll
        for (int k = 0; k < 8; ++k) a = fmaf(pg[o*8+k], we[k*3+c], a);
        matsL[80 + t] = a;                       // M1 staging
        float av = 0.f, bv = 0.f;
        #pragma unroll
        for (int k = 0; k < 8; ++k) {
            float m1 = matsL[80 + k*3 + c];      // same-wave LDS RAW: lockstep-ordered
            av = fmaf(psx[o*8+k], m1, av);
            bv = fmaf(psy[o*8+k], m1, bv);
        }
        av *= invsum; bv *= invsum;              // fold gaussian normalization
        int pi = ((o>>1)*3 + c)*2 + (o&1);
        matsL[pi]      = av;
        matsL[24 + pi] = bv;
    } else if (t < 32) {
        int o = t - 24;
        float hi = hight[o], lo = lowt[o];
        float d = K2E * 0.5f * (hi - lo);
        matsL[48+o] = K2E * 0.5f * (hi + lo);    // midK
        matsL[56+o] = exp2f(d);                  // PH
        matsL[64+o] = exp2f(-d);                 // PL
        matsL[72+o] = 0.5f * wm[o];              // wmh
    }

    const float* xb = x + (size_t)b*3*HWp;

    // ---- phase A: x window (reflect) -> sm1 ----
    if (inter) {
        const float* xo = xb + (size_t)(y0-4)*512 + (x0-4);
        for (int i = t; i < 3*XW*10; i += NT) {
            int c = i/400; int j = i - c*400; int r = j/10; int q = j - r*10;
            float4 v = *(const float4*)(xo + (size_t)c*HWp + r*512 + q*4);
            *(float4*)&sm1[c*(XW*XW) + r*XW + q*4] = v;
        }
    } else {
        for (int i = t; i < XW*XW; i += NT) {
            int r = i/XW, cc = i - r*XW;
            size_t off = (size_t)refl(y0-4+r,512)*512 + refl(x0-4+cc,512);
            #pragma unroll
            for (int c = 0; c < 3; ++c)
                sm1[c*(XW*XW)+i] = xb[(size_t)c*HWp + off];
        }
    }
    __syncthreads();

    // ---- phase B: separable gaussian (unnormalized) -> blb ----
    if (inter) {
        if (t < 494) {
            int g = t/38, cb = t - g*38, r0 = 3*g;
            #pragma unroll
            for (int c = 0; c < 3; ++c) {
                const float* col = &sm1[c*(XW*XW) + cb];
                float* bo = &blb[c*(BW*BP) + cb];
                float v0 = col[r0*XW], v1 = col[r0*XW+1], v2 = col[r0*XW+2];
                float rp0 = fmaf(e1f, v0 + v2, v1);
                v0 = col[(r0+1)*XW]; v1 = col[(r0+1)*XW+1]; v2 = col[(r0+1)*XW+2];
                float rp1 = fmaf(e1f, v0 + v2, v1);
                #pragma unroll
                for (int ir = 0; ir < 3; ++ir) {
                    int r = r0 + ir;
                    if (r < BW) {
                        v0 = col[(r+2)*XW]; v1 = col[(r+2)*XW+1]; v2 = col[(r+2)*XW+2];
                        float rp2 = fmaf(e1f, v0 + v2, v1);
                        bo[r*BP] = fmaf(e1f, rp0 + rp2, rp1);
                        rp0 = rp1; rp1 = rp2;
                    }
                }
            }
        }
    } else {
        for (int i = t; i < BW*BW; i += NT) {
            int r = i/BW, cc = i - r*BW;
            int iy = refl(y0-3+r,512) - (y0-4);
            int ix = refl(x0-3+cc,512) - (x0-4);
            const int base = iy*XW + ix;
            #pragma unroll
            for (int c = 0; c < 3; ++c) {
                const float* xp = &sm1[c*(XW*XW) + base];
                float crn = xp[-XW-1]+xp[-XW+1]+xp[XW-1]+xp[XW+1];
                float edg = xp[-XW]+xp[-1]+xp[1]+xp[XW];
                blb[c*(BW*BP) + r*BP + cc] = fmaf(e12f, crn, fmaf(e1f, edg, xp[0]));
            }
        }
    }
    __syncthreads();

    // ---- phase C: sobel via rolling regs -> mag/octant (regs, pinned) + s -> sS ----
    f2 mg2[3][4];
    unsigned qk[3];
    const int gC = t/36, csC = t - gC*36, r0C = 3*gC;
    const bool actC = (t < 432);
    if (actC) {
        f2 A2[12], B2[12];
        #pragma unroll
        for (int j = 0; j < 12; ++j) {
            A2[j] = ldsU2(matsL + 2*j);
            B2[j] = ldsU2(matsL + 24 + 2*j);
        }
        float D0[3], D1[3], E0[3], E1[3];
        #pragma unroll
        for (int c = 0; c < 3; ++c) {
            const float* blc = &blb[c*(BW*BP) + csC];
            float p0 = blc[r0C*BP],     p1 = blc[r0C*BP+1],     p2 = blc[r0C*BP+2];
            float q0 = blc[(r0C+1)*BP], q1 = blc[(r0C+1)*BP+1], q2 = blc[(r0C+1)*BP+2];
            D0[c] = p2-p0; E0[c] = fmaf(0.5f, p0+p2, p1);
            D1[c] = q2-q0; E1[c] = fmaf(0.5f, q0+q2, q1);
        }
        #pragma unroll
        for (int ir = 0; ir < 3; ++ir) {
            float txv[3], tyv[3];
            #pragma unroll
            for (int c = 0; c < 3; ++c) {
                const float* wr = &blb[c*(BW*BP) + (r0C+2+ir)*BP + csC];
                float w0 = wr[0], w1 = wr[1], w2 = wr[2];
                float D2 = w2-w0, E2 = fmaf(0.5f, w0+w2, w1);
                txv[c] = fmaf(0.5f, D0[c]+D2, D1[c]);
                tyv[c] = E2 - E0[c];
                D0[c] = D1[c]; D1[c] = D2; E0[c] = E1[c]; E1[c] = E2;
            }
            float s = 0.f;
            unsigned pk = 0;
            #pragma unroll
            for (int j = 0; j < 4; ++j) {
                float gxa = fmaf(A2[j*3].x, txv[0], fmaf(A2[j*3+1].x, txv[1], A2[j*3+2].x*txv[2]));
                float gxb = fmaf(A2[j*3].y, txv[0], fmaf(A2[j*3+1].y, txv[1], A2[j*3+2].y*txv[2]));
                float gya = fmaf(B2[j*3].x, tyv[0], fmaf(B2[j*3+1].x, tyv[1], B2[j*3+2].x*tyv[2]));
                float gyb = fmaf(B2[j*3].y, tyv[0], fmaf(B2[j*3+1].y, tyv[1], B2[j*3+2].y*tyv[2]));
                float gx2a = gxa*gxa, gy2a = gya*gya;
                float gx2b = gxb*gxb, gy2b = gyb*gyb;
                f2 m;
                m.x = __builtin_amdgcn_sqrtf(gx2a + gy2a + 1e-10f);
                m.y = __builtin_amdgcn_sqrtf(gx2b + gy2b + 1e-10f);
                mg2[ir][j] = m;
                s += m.x + m.y;
                unsigned d0 = 1u | (((__float_as_uint(gxa) ^ __float_as_uint(gya)) >> 30) & 2u);
                unsigned q0 = (gx2a <= T2q*gy2a) ? 2u : d0;
                q0 = (gy2a <= T2q*gx2a) ? 0u : q0;
                unsigned d1 = 1u | (((__float_as_uint(gxb) ^ __float_as_uint(gyb)) >> 30) & 2u);
                unsigned q1 = (gx2b <= T2q*gy2b) ? 2u : d1;
                q1 = (gy2b <= T2q*gx2b) ? 0u : q1;
                pk |= (q0 << (4*j)) | (q1 << (4*j+2));
            }
            qk[ir] = pk;
            #pragma unroll
            for (int j = 0; j < 4; ++j) { asm volatile("" : "+v"(mg2[ir][j])); }
            asm volatile("" : "+v"(qk[ir]));
            int rr = r0C + ir;
            int gy_ = y0-2+rr, gx_ = x0-2+csC;
            bool inimg = ((unsigned)gy_ < 512u) && ((unsigned)gx_ < 512u);
            sm1[rr*SP + csC] = inimg ? s : 0.f;   // sS (x window dead)
        }
    }
    __syncthreads();

    // ---- phase D: NMS + single-exp2 double-sigmoid + merge -> mS ----
    bool anyL = false;
    {
        const float* sS = sm1;
        float* mS = sm1 + SG*SP;
        if (actC && csC >= 1 && csC <= 34) {
            f2 mid2[4], ph2[4], pl2[4], wm2[4];
            #pragma unroll
            for (int j = 0; j < 4; ++j) {
                mid2[j] = ldsU2(matsL + 48 + 2*j);
                ph2[j]  = ldsU2(matsL + 56 + 2*j);
                pl2[j]  = ldsU2(matsL + 64 + 2*j);
                wm2[j]  = ldsU2(matsL + 72 + 2*j);
            }
            int ra = r0C-1 < 0 ? 0 : r0C-1;
            const float* pa = &sS[ra*SP + csC];
            const float* pb = &sS[r0C*SP + csC];
            const float* pc = &sS[(r0C+1)*SP + csC];
            float l0=pa[-1], c0=pa[0], r0v=pa[1];
            float l1=pb[-1], c1=pb[0], r1v=pb[1];
            float l2=pc[-1], c2=pc[0], r2v=pc[1];
            #pragma unroll
            for (int ir = 0; ir < 3; ++ir) {
                int r = r0C + ir;
                if (r >= 1 && r <= 34) {
                    float sc = c1;
                    unsigned mask = 0;
                    mask |= ((sc > r1v) && (sc > l1)) ? 1u : 0u;  // E/W
                    mask |= ((sc > r2v) && (sc > l0)) ? 2u : 0u;  // SE/NW
                    mask |= ((sc > c2)  && (sc > c0)) ? 4u : 0u;  // S/N
                    mask |= ((sc > l2)  && (sc > r0v)) ? 8u : 0u; // SW/NE
                    unsigned pk = qk[ir];
                    float m = 0.f;
                    #pragma unroll
                    for (int j = 0; j < 4; ++j) {
                        unsigned ii = pk >> (4*j);
                        float n0 = ((mask >> (ii & 3u)) & 1u)      ? mg2[ir][j].x : 0.f;
                        float n1 = ((mask >> ((ii>>2) & 3u)) & 1u) ? mg2[ir][j].y : 0.f;
                        float e0 = EXP2F(fmaf(n0, -K2E, mid2[j].x));
                        float e1 = EXP2F(fmaf(n1, -K2E, mid2[j].y));
                        float sh0 = __builtin_amdgcn_rcpf(fmaf(e0, ph2[j].x, 1.f));
                        float sl0 = __builtin_amdgcn_rcpf(fmaf(e0, pl2[j].x, 1.f));
                        float sh1 = __builtin_amdgcn_rcpf(fmaf(e1, ph2[j].y, 1.f));
                        float sl1 = __builtin_amdgcn_rcpf(fmaf(e1, pl2[j].y, 1.f));
                        m = fmaf(wm2[j].x, sh0 + sl0, m);
                        m = fmaf(wm2[j].y, sh1 + sl1, m);
                    }
                    mS[(r-1)*MP + (csC-1)] = m;
                    anyL |= (m == 1.0f);
                }
                if (ir < 2) {
                    int rn = r0C + 2 + ir; rn = rn > 35 ? 35 : rn;
                    const float* pn = &sS[rn*SP + csC];
                    l0=l1; c0=c1; r0v=r1v;
                    l1=l2; c1=c2; r1v=r2v;
                    l2=pn[-1]; c2=pn[0]; r2v=pn[1];
                }
            }
        }
    }
    if (anyL) anyS = 1;
    __syncthreads();

    // ---- phase E: one-step hysteresis (reflect) -> out; vector-zero fast path ----
    {
        const float* mS = sm1 + SG*SP;
        float* op = out + (size_t)b*HWp;
        if (anyS == 0) {
            if (t < 256) {
                int row = t >> 3, q = t & 7;
                float4 z = {0.f, 0.f, 0.f, 0.f};
                *(float4*)(op + (size_t)(y0+row)*512 + x0 + q*4) = z;
            }
        } else {
            for (int i2 = t; i2 < TS*TS; i2 += NT) {
                int ty_ = i2>>5, tx_ = i2&31;
                int y = y0 + ty_, xg = x0 + tx_;
                const float* mp = &mS[(ty_+1)*MP + (tx_+1)];
                float mc = mp[0];
                float hy = 0.f;
                if (inter) {
                    #pragma unroll
                    for (int dy = -1; dy <= 1; ++dy)
                        #pragma unroll
                        for (int dx = -1; dx <= 1; ++dx)
                            hy += (mp[dy*MP+dx] == 1.0f) ? 1.25f : 0.f;
                } else {
                    #pragma unroll
                    for (int dy = -1; dy <= 1; ++dy)
                        #pragma unroll
                        for (int dx = -1; dx <= 1; ++dx) {
                            int ly = refl(y+dy,512) - (y0-1);
                            int lx = refl(xg+dx,512) - (x0-1);
                            hy += (mS[ly*MP+lx] == 1.0f) ? 1.25f : 0.f;
                        }
                }
                float strong = (mc == 1.0f) ? mc : 0.f;
                op[(size_t)y*512 + xg] =
                    (((hy > 1.0f) && (mc == 0.5f)) ? mc : 0.f) + strong;
            }
        }
    }
}

extern "C" void kernel_launch(void* const* d_in, const int* in_sizes, int n_in,
                              void* d_out, int out_size, void* d_ws, size_t ws_size,
                              hipStream_t stream) {
    const float* x    = (const float*)d_in[0];
    const float* we   = (const float*)d_in[1];
    const float* pg   = (const float*)d_in[2];
    const float* psx  = (const float*)d_in[3];
    const float* psy  = (const float*)d_in[4];
    const float* wm   = (const float*)d_in[5];
    const float* lowt = (const float*)d_in[6];
    const float* hit  = (const float*)d_in[7];
    float* outp = (float*)d_out;

    // gaussian 3x3 (sigma=3): separable outer([e1,1,e1]) since e2 = e1^2
    double e1 = exp(-1.0/18.0), e2 = exp(-2.0/18.0);
    double sum = 1.0 + 4.0*e1 + 4.0*e2;
    float e1f = (float)e1, e12f = (float)e2, invsum = (float)(1.0/sum);

    k_fused<<<dim3(512/TS, 512/TS, Bsz), dim3(NT), 0, stream>>>(
        x, we, pg, psx, psy, wm, lowt, hit, outp, e1f, e12f, invsum);
}

// Round 11
// 45.068 us; speedup vs baseline: 1.0958x; 1.0307x over previous
//
#include <hip/hip_runtime.h>
#include <math.h>

#define Bsz 8
#define HWp (512*512)
#define TS 32
#define SG 36          // s rows/cols
#define SP 37          // s row stride (padded)
#define MG 34          // m rows/cols
#define MP 35          // m row stride (padded)
#define XW 40          // x window rows/cols
#define BW 38          // blur rows/cols
#define BP 39          // blur row stride (padded)
#define NT 512
#define K2E 1442.6950408889634f   // 1000*log2(e)
#define T2q 0.17157287525380993f  // tan^2(22.5 deg)

typedef float f2 __attribute__((ext_vector_type(2)));

#if __has_builtin(__builtin_amdgcn_exp2f)
#define EXP2F(x) __builtin_amdgcn_exp2f(x)
#else
#define EXP2F(x) __expf(0.6931471805599453f*(x))
#endif

__device__ __forceinline__ int refl(int i, int n) {
    i = (i < 0) ? -i : i;
    return (i >= n) ? (2*n - 2 - i) : i;
}
__device__ __forceinline__ float ldsUf(float v) {
    return __uint_as_float(__builtin_amdgcn_readfirstlane(__float_as_uint(v)));
}
__device__ __forceinline__ f2 ldsU2(const float* p) {
    f2 v = *(const f2*)p;
    f2 r; r.x = ldsUf(v.x); r.y = ldsUf(v.y);
    return r;
}

// matsL layout (floats):
//  [0..23]  Apk pairs (A[2j][k],A[2j+1][k]) at [(j*3+k)*2], A=(Psx@(Pg@We))/sum
//  [24..47] Bpk pairs, B=(Psy@(Pg@We))/sum
//  [48..55] midK  [56..63] PH  [64..71] PL  [72..79] 0.5*wm
//  [80..103] M1 staging
__global__ __launch_bounds__(NT) void k_fused(
    const float* __restrict__ x,
    const float* __restrict__ we, const float* __restrict__ pg,
    const float* __restrict__ psx, const float* __restrict__ psy,
    const float* __restrict__ wm, const float* __restrict__ lowt,
    const float* __restrict__ hight,
    float* __restrict__ out, float e1f, float e12f, float invsum)
{
    __shared__ float sm1[3*XW*XW];   // A/B: x window ; C+: sS(36x37) | mS(34x35)
    __shared__ float blb[3*BW*BP];   // unnormalized blur, padded stride
    __shared__ __align__(16) float matsL[104];
    __shared__ int anyS;

    const int b  = blockIdx.z;
    const int x0 = blockIdx.x*TS, y0 = blockIdx.y*TS;
    const int t  = threadIdx.x;
    const bool inter = (blockIdx.x > 0) && ((int)blockIdx.x < (int)gridDim.x-1) &&
                       (blockIdx.y > 0) && ((int)blockIdx.y < (int)gridDim.y-1);

    if (t == 0) anyS = 0;

    // ---- prologue (wave 0 lanes 0..31): fold mats + thresholds into matsL ----
    if (t < 24) {
        int o = t/3, c = t - o*3;
        float a = 0.f;
        #pragma unroll
        for (int k = 0; k < 8; ++k) a = fmaf(pg[o*8+k], we[k*3+c], a);
        matsL[80 + t] = a;                       // M1 staging
        float av = 0.f, bv = 0.f;
        #pragma unroll
        for (int k = 0; k < 8; ++k) {
            float m1 = matsL[80 + k*3 + c];      // same-wave LDS RAW: lockstep-ordered
            av = fmaf(psx[o*8+k], m1, av);
            bv = fmaf(psy[o*8+k], m1, bv);
        }
        av *= invsum; bv *= invsum;              // fold gaussian normalization
        int pi = ((o>>1)*3 + c)*2 + (o&1);
        matsL[pi]      = av;
        matsL[24 + pi] = bv;
    } else if (t < 32) {
        int o = t - 24;
        float hi = hight[o], lo = lowt[o];
        float d = K2E * 0.5f * (hi - lo);
        matsL[48+o] = K2E * 0.5f * (hi + lo);    // midK
        matsL[56+o] = exp2f(d);                  // PH
        matsL[64+o] = exp2f(-d);                 // PL
        matsL[72+o] = 0.5f * wm[o];              // wmh
    }

    const float* xb = x + (size_t)b*3*HWp;

    // ---- phase A: x window (reflect) -> sm1 ----
    if (inter) {
        const float* xo = xb + (size_t)(y0-4)*512 + (x0-4);
        for (int i = t; i < 3*XW*10; i += NT) {
            int c = i/400; int j = i - c*400; int r = j/10; int q = j - r*10;
            float4 v = *(const float4*)(xo + (size_t)c*HWp + r*512 + q*4);
            *(float4*)&sm1[c*(XW*XW) + r*XW + q*4] = v;
        }
    } else {
        for (int i = t; i < XW*XW; i += NT) {
            int r = i/XW, cc = i - r*XW;
            size_t off = (size_t)refl(y0-4+r,512)*512 + refl(x0-4+cc,512);
            #pragma unroll
            for (int c = 0; c < 3; ++c)
                sm1[c*(XW*XW)+i] = xb[(size_t)c*HWp + off];
        }
    }
    __syncthreads();

    // ---- phase B: separable gaussian (unnormalized) -> blb ----
    if (inter) {
        if (t < 494) {
            int g = t/38, cb = t - g*38, r0 = 3*g;
            #pragma unroll
            for (int c = 0; c < 3; ++c) {
                const float* col = &sm1[c*(XW*XW) + cb];
                float* bo = &blb[c*(BW*BP) + cb];
                float v0 = col[r0*XW], v1 = col[r0*XW+1], v2 = col[r0*XW+2];
                float rp0 = fmaf(e1f, v0 + v2, v1);
                v0 = col[(r0+1)*XW]; v1 = col[(r0+1)*XW+1]; v2 = col[(r0+1)*XW+2];
                float rp1 = fmaf(e1f, v0 + v2, v1);
                #pragma unroll
                for (int ir = 0; ir < 3; ++ir) {
                    int r = r0 + ir;
                    if (r < BW) {
                        v0 = col[(r+2)*XW]; v1 = col[(r+2)*XW+1]; v2 = col[(r+2)*XW+2];
                        float rp2 = fmaf(e1f, v0 + v2, v1);
                        bo[r*BP] = fmaf(e1f, rp0 + rp2, rp1);
                        rp0 = rp1; rp1 = rp2;
                    }
                }
            }
        }
    } else {
        for (int i = t; i < BW*BW; i += NT) {
            int r = i/BW, cc = i - r*BW;
            int iy = refl(y0-3+r,512) - (y0-4);
            int ix = refl(x0-3+cc,512) - (x0-4);
            const int base = iy*XW + ix;
            #pragma unroll
            for (int c = 0; c < 3; ++c) {
                const float* xp = &sm1[c*(XW*XW) + base];
                float crn = xp[-XW-1]+xp[-XW+1]+xp[XW-1]+xp[XW+1];
                float edg = xp[-XW]+xp[-1]+xp[1]+xp[XW];
                blb[c*(BW*BP) + r*BP + cc] = fmaf(e12f, crn, fmaf(e1f, edg, xp[0]));
            }
        }
    }
    __syncthreads();

    // ---- phase C: sobel via rolling regs -> mag/octant (regs, pinned) + s -> sS ----
    // 504-thread map: 36 cols x 14 groups; groups 0..7 own 3 rows, 8..13 own 2 rows.
    f2 mg2[3][4];
    unsigned qk[3];
    const int gC = t/36, csC = t - gC*36;
    const bool actC = (t < 504);
    const int nrC  = (gC < 8) ? 3 : 2;
    const int r0C  = (gC < 8) ? 3*gC : 24 + 2*(gC-8);
    if (actC) {
        f2 A2[12], B2[12];
        #pragma unroll
        for (int j = 0; j < 12; ++j) {
            A2[j] = ldsU2(matsL + 2*j);
            B2[j] = ldsU2(matsL + 24 + 2*j);
        }
        float D0[3], D1[3], E0[3], E1[3];
        #pragma unroll
        for (int c = 0; c < 3; ++c) {
            const float* blc = &blb[c*(BW*BP) + csC];
            float p0 = blc[r0C*BP],     p1 = blc[r0C*BP+1],     p2 = blc[r0C*BP+2];
            float q0 = blc[(r0C+1)*BP], q1 = blc[(r0C+1)*BP+1], q2 = blc[(r0C+1)*BP+2];
            D0[c] = p2-p0; E0[c] = fmaf(0.5f, p0+p2, p1);
            D1[c] = q2-q0; E1[c] = fmaf(0.5f, q0+q2, q1);
        }
        #pragma unroll
        for (int ir = 0; ir < 3; ++ir) {
            if (ir < nrC) {
                float txv[3], tyv[3];
                #pragma unroll
                for (int c = 0; c < 3; ++c) {
                    const float* wr = &blb[c*(BW*BP) + (r0C+2+ir)*BP + csC];
                    float w0 = wr[0], w1 = wr[1], w2 = wr[2];
                    float D2 = w2-w0, E2 = fmaf(0.5f, w0+w2, w1);
                    txv[c] = fmaf(0.5f, D0[c]+D2, D1[c]);
                    tyv[c] = E2 - E0[c];
                    D0[c] = D1[c]; D1[c] = D2; E0[c] = E1[c]; E1[c] = E2;
                }
                float s = 0.f;
                unsigned pk = 0;
                #pragma unroll
                for (int j = 0; j < 4; ++j) {
                    float gxa = fmaf(A2[j*3].x, txv[0], fmaf(A2[j*3+1].x, txv[1], A2[j*3+2].x*txv[2]));
                    float gxb = fmaf(A2[j*3].y, txv[0], fmaf(A2[j*3+1].y, txv[1], A2[j*3+2].y*txv[2]));
                    float gya = fmaf(B2[j*3].x, tyv[0], fmaf(B2[j*3+1].x, tyv[1], B2[j*3+2].x*tyv[2]));
                    float gyb = fmaf(B2[j*3].y, tyv[0], fmaf(B2[j*3+1].y, tyv[1], B2[j*3+2].y*tyv[2]));
                    float gx2a = gxa*gxa, gy2a = gya*gya;
                    float gx2b = gxb*gxb, gy2b = gyb*gyb;
                    f2 m;
                    m.x = __builtin_amdgcn_sqrtf(gx2a + gy2a + 1e-10f);
                    m.y = __builtin_amdgcn_sqrtf(gx2b + gy2b + 1e-10f);
                    mg2[ir][j] = m;
                    s += m.x + m.y;
                    unsigned d0 = 1u | (((__float_as_uint(gxa) ^ __float_as_uint(gya)) >> 30) & 2u);
                    unsigned q0 = (gx2a <= T2q*gy2a) ? 2u : d0;
                    q0 = (gy2a <= T2q*gx2a) ? 0u : q0;
                    unsigned d1 = 1u | (((__float_as_uint(gxb) ^ __float_as_uint(gyb)) >> 30) & 2u);
                    unsigned q1 = (gx2b <= T2q*gy2b) ? 2u : d1;
                    q1 = (gy2b <= T2q*gx2b) ? 0u : q1;
                    pk |= (q0 << (4*j)) | (q1 << (4*j+2));
                }
                qk[ir] = pk;
                #pragma unroll
                for (int j = 0; j < 4; ++j) { asm volatile("" : "+v"(mg2[ir][j])); }
                asm volatile("" : "+v"(qk[ir]));
                int rr = r0C + ir;
                int gy_ = y0-2+rr, gx_ = x0-2+csC;
                bool inimg = ((unsigned)gy_ < 512u) && ((unsigned)gx_ < 512u);
                sm1[rr*SP + csC] = inimg ? s : 0.f;   // sS (x window dead)
            }
        }
    }
    __syncthreads();

    // ---- phase D: NMS + single-exp2 double-sigmoid + merge -> mS ----
    bool anyL = false;
    {
        const float* sS = sm1;
        float* mS = sm1 + SG*SP;
        if (actC && csC >= 1 && csC <= 34) {
            f2 mid2[4], ph2[4], pl2[4], wm2[4];
            #pragma unroll
            for (int j = 0; j < 4; ++j) {
                mid2[j] = ldsU2(matsL + 48 + 2*j);
                ph2[j]  = ldsU2(matsL + 56 + 2*j);
                pl2[j]  = ldsU2(matsL + 64 + 2*j);
                wm2[j]  = ldsU2(matsL + 72 + 2*j);
            }
            int ra = r0C-1 < 0 ? 0 : r0C-1;
            const float* pa = &sS[ra*SP + csC];
            const float* pb = &sS[r0C*SP + csC];
            const float* pc = &sS[(r0C+1)*SP + csC];
            float l0=pa[-1], c0=pa[0], r0v=pa[1];
            float l1=pb[-1], c1=pb[0], r1v=pb[1];
            float l2=pc[-1], c2=pc[0], r2v=pc[1];
            #pragma unroll
            for (int ir = 0; ir < 3; ++ir) {
                if (ir < nrC) {
                    int r = r0C + ir;
                    if (r >= 1 && r <= 34) {
                        float sc = c1;
                        unsigned mask = 0;
                        mask |= ((sc > r1v) && (sc > l1)) ? 1u : 0u;  // E/W
                        mask |= ((sc > r2v) && (sc > l0)) ? 2u : 0u;  // SE/NW
                        mask |= ((sc > c2)  && (sc > c0)) ? 4u : 0u;  // S/N
                        mask |= ((sc > l2)  && (sc > r0v)) ? 8u : 0u; // SW/NE
                        unsigned pk = qk[ir];
                        float m = 0.f;
                        #pragma unroll
                        for (int j = 0; j < 4; ++j) {
                            unsigned ii = pk >> (4*j);
                            float n0 = ((mask >> (ii & 3u)) & 1u)      ? mg2[ir][j].x : 0.f;
                            float n1 = ((mask >> ((ii>>2) & 3u)) & 1u) ? mg2[ir][j].y : 0.f;
                            float e0 = EXP2F(fmaf(n0, -K2E, mid2[j].x));
                            float e1 = EXP2F(fmaf(n1, -K2E, mid2[j].y));
                            float sh0 = __builtin_amdgcn_rcpf(fmaf(e0, ph2[j].x, 1.f));
                            float sl0 = __builtin_amdgcn_rcpf(fmaf(e0, pl2[j].x, 1.f));
                            float sh1 = __builtin_amdgcn_rcpf(fmaf(e1, ph2[j].y, 1.f));
                            float sl1 = __builtin_amdgcn_rcpf(fmaf(e1, pl2[j].y, 1.f));
                            m = fmaf(wm2[j].x, sh0 + sl0, m);
                            m = fmaf(wm2[j].y, sh1 + sl1, m);
                        }
                        mS[(r-1)*MP + (csC-1)] = m;
                        anyL |= (m == 1.0f);
                    }
                    if (ir < 2) {
                        int rn = r0C + 2 + ir; rn = rn > 35 ? 35 : rn;
                        const float* pn = &sS[rn*SP + csC];
                        l0=l1; c0=c1; r0v=r1v;
                        l1=l2; c1=c2; r1v=r2v;
                        l2=pn[-1]; c2=pn[0]; r2v=pn[1];
                    }
                }
            }
        }
    }
    if (anyL) anyS = 1;
    __syncthreads();

    // ---- phase E: one-step hysteresis (reflect) -> out; vector-zero fast path ----
    {
        const float* mS = sm1 + SG*SP;
        float* op = out + (size_t)b*HWp;
        if (anyS == 0) {
            if (t < 256) {
                int row = t >> 3, q = t & 7;
                float4 z = {0.f, 0.f, 0.f, 0.f};
                *(float4*)(op + (size_t)(y0+row)*512 + x0 + q*4) = z;
            }
        } else {
            for (int i2 = t; i2 < TS*TS; i2 += NT) {
                int ty_ = i2>>5, tx_ = i2&31;
                int y = y0 + ty_, xg = x0 + tx_;
                const float* mp = &mS[(ty_+1)*MP + (tx_+1)];
                float mc = mp[0];
                float hy = 0.f;
                if (inter) {
                    #pragma unroll
                    for (int dy = -1; dy <= 1; ++dy)
                        #pragma unroll
                        for (int dx = -1; dx <= 1; ++dx)
                            hy += (mp[dy*MP+dx] == 1.0f) ? 1.25f : 0.f;
                } else {
                    #pragma unroll
                    for (int dy = -1; dy <= 1; ++dy)
                        #pragma unroll
                        for (int dx = -1; dx <= 1; ++dx) {
                            int ly = refl(y+dy,512) - (y0-1);
                            int lx = refl(xg+dx,512) - (x0-1);
                            hy += (mS[ly*MP+lx] == 1.0f) ? 1.25f : 0.f;
                        }
                }
                float strong = (mc == 1.0f) ? mc : 0.f;
                op[(size_t)y*512 + xg] =
                    (((hy > 1.0f) && (mc == 0.5f)) ? mc : 0.f) + strong;
            }
        }
    }
}

extern "C" void kernel_launch(void* const* d_in, const int* in_sizes, int n_in,
                              void* d_out, int out_size, void* d_ws, size_t ws_size,
                              hipStream_t stream) {
    const float* x    = (const float*)d_in[0];
    const float* we   = (const float*)d_in[1];
    const float* pg   = (const float*)d_in[2];
    const float* psx  = (const float*)d_in[3];
    const float* psy  = (const float*)d_in[4];
    const float* wm   = (const float*)d_in[5];
    const float* lowt = (const float*)d_in[6];
    const float* hit  = (const float*)d_in[7];
    float* outp = (float*)d_out;

    // gaussian 3x3 (sigma=3): separable outer([e1,1,e1]) since e2 = e1^2
    double e1 = exp(-1.0/18.0), e2 = exp(-2.0/18.0);
    double sum = 1.0 + 4.0*e1 + 4.0*e2;
    float e1f = (float)e1, e12f = (float)e2, invsum = (float)(1.0/sum);

    k_fused<<<dim3(512/TS, 512/TS, Bsz), dim3(NT), 0, stream>>>(
        x, we, pg, psx, psy, wm, lowt, hit, outp, e1f, e12f, invsum);
}